// Round 2
// baseline (176.733 us; speedup 1.0000x reference)
//
#include <hip/hip_runtime.h>

// Problem constants (from reference setup_inputs)
#define B 8
#define C 64
#define H 152
#define W 272
#define HW (H * W)          // 41344
#define K 500
#define KP 512              // K padded to tile multiple
#define ALPHA 0.25f
#define PROB_MIN 1e-4f

typedef __attribute__((ext_vector_type(8))) short short8;   // 8 bf16 (4 VGPRs)
typedef __attribute__((ext_vector_type(4))) float floatx4;  // 4 fp32 acc

// fp32 -> bf16 round-to-nearest-even
__device__ __forceinline__ unsigned short f32_to_bf16(float f) {
    union { float f; unsigned int u; } v; v.f = f;
    unsigned int r = v.u + 0x7FFFu + ((v.u >> 16) & 1u);
    return (unsigned short)(r >> 16);
}

// ---------------------------------------------------------------------------
// Kernel 1: masked gather -> bf16 feats [B, KP, C]; zero-pads rows K..KP-1.
// Each thread gathers BOTH cur and pre for its (row, channel) -> 2
// independent scattered loads in flight per thread, 4096 waves, 1024 blocks.
// Index/mask loads are wave-uniform (row = t>>6) -> forced to SGPR via
// readfirstlane so the scattered-load offset is scalar.
// Also zero-initializes the scalar output (poisoned before replay).
// ---------------------------------------------------------------------------
__global__ __launch_bounds__(256) void gather_kernel(
    const float* __restrict__ cur_reid,
    const float* __restrict__ pre_reid,
    const int* __restrict__ cur_inds,
    const int* __restrict__ pre_inds,
    const int* __restrict__ cur_circ,
    const int* __restrict__ pre_circ,
    const int* __restrict__ tmask,
    unsigned short* __restrict__ curf,
    unsigned short* __restrict__ pref,
    float* __restrict__ out)
{
    const int t = threadIdx.x;          // 0 .. 255
    const int r = t >> 6;               // row within block, 0..3 (wave-uniform)
    const int c = t & 63;               // channel = lane
    const int bk = blockIdx.x * 4 + r;  // 0 .. B*KP-1

    if (bk == 0 && t == 0) out[0] = 0.0f;  // before loss kernel (stream order)

    const int b = bk >> 9;              // /KP
    const int k = bk & (KP - 1);
    const size_t orow = (size_t)bk * C + c;

    if (k >= K) {                       // padding rows -> zero both tensors
        curf[orow] = 0;
        pref[orow] = 0;
        return;
    }

    const int bk_in = b * K + k;        // index into [B,K] arrays (wave-uniform)
    const int m  = tmask[bk_in];
    int ci = m ? cur_inds[bk_in] : cur_circ[bk_in];
    int pi = m ? pre_inds[bk_in] : pre_circ[bk_in];
    // values are wave-uniform: hoist to SGPR (provably same result)
    ci = __builtin_amdgcn_readfirstlane(ci);
    pi = __builtin_amdgcn_readfirstlane(pi);

    const size_t plane = ((size_t)(b * C + c)) * HW;
    const float cv = cur_reid[plane + ci];   // two independent scattered loads
    const float pv = pre_reid[plane + pi];   // -> both in flight together

    curf[orow] = f32_to_bf16(cv);
    pref[orow] = f32_to_bf16(pv);
}

// ---------------------------------------------------------------------------
// Kernel 2: per-wave 16x16 tile of sim via MFMA 16x16x32 bf16 (2 MFMAs, K=64),
// fragments loaded directly from global (feat fits in L1/L2), fused focal
// loss + block reduce + one atomicAdd per block.
// Diagonal handling hoisted to tile granularity (wave-uniform branch);
// 97% of tiles skip the per-element gi==gj compare + tmask load path.
// ---------------------------------------------------------------------------
__device__ __forceinline__ float focal_term(float x, int gt, bool valid)
{
    if (!valid) return 0.0f;
    const float sim = 1.0f / (1.0f + __expf(-x));
    float p = gt ? sim : 1.0f - sim;
    p = fminf(fmaxf(p, PROB_MIN), 1.0f);
    const float a = gt ? ALPHA : (1.0f - ALPHA);
    const float om = 1.0f - p;
    return a * om * om * (-__logf(p));
}

#define LOSS_THREADS 1024   // 16 waves per block -> 16 tiles per block

__global__ __launch_bounds__(LOSS_THREADS) void loss_kernel(
    const unsigned short* __restrict__ curf,
    const unsigned short* __restrict__ pref,
    const int* __restrict__ tmask,
    float* __restrict__ out)
{
    __shared__ float wsum[LOSS_THREADS / 64];

    const int t    = threadIdx.x;
    const int wave = t >> 6;
    const int lane = t & 63;

    // Flat tile id -> (b, ti, tj); tiles: 32 x 32 per batch, 8 batches = 8192.
    const int tile = blockIdx.x * (LOSS_THREADS / 64) + wave;
    const int b    = tile >> 10;
    const int rem  = tile & 1023;
    const int ti   = rem >> 5;
    const int tj   = rem & 31;

    const int m16  = lane & 15;   // A-row / B-row (=sim col) within tile
    const int quad = lane >> 4;   // 0..3

    // A frag: curf[b][ti*16 + m16][quad*8 + (0..7)]  (+32 for second MFMA)
    const unsigned short* pa = curf + (((size_t)(b * KP + ti * 16 + m16)) * C + quad * 8);
    const unsigned short* pb = pref + (((size_t)(b * KP + tj * 16 + m16)) * C + quad * 8);
    const short8 a0 = *(const short8*)pa;
    const short8 a1 = *(const short8*)(pa + 32);
    const short8 b0 = *(const short8*)pb;
    const short8 b1 = *(const short8*)(pb + 32);

    floatx4 acc = {0.f, 0.f, 0.f, 0.f};
    acc = __builtin_amdgcn_mfma_f32_16x16x32_bf16(a0, b0, acc, 0, 0, 0);
    acc = __builtin_amdgcn_mfma_f32_16x16x32_bf16(a1, b1, acc, 0, 0, 0);

    // C/D layout: col = lane&15, row = quad*4 + reg   [measured m89/m91]
    const int gj = tj * 16 + m16;
    float s = 0.f;
    if (ti == tj) {
        // diagonal tile: per-element gt from tmask where gi==gj
#pragma unroll
        for (int r = 0; r < 4; ++r) {
            const int gi = ti * 16 + quad * 4 + r;
            const int gt = (gi == gj) ? tmask[b * K + gi] : 0;
            s += focal_term(acc[r], gt, (gi < K) && (gj < K));
        }
    } else {
        // off-diagonal tile (97% of waves): gt == 0 always, no tmask touch
#pragma unroll
        for (int r = 0; r < 4; ++r) {
            const int gi = ti * 16 + quad * 4 + r;
            s += focal_term(acc[r], 0, (gi < K) && (gj < K));
        }
    }

    // wave64 butterfly, then cross-wave via LDS, one atomic per block
#pragma unroll
    for (int o = 32; o > 0; o >>= 1) s += __shfl_down(s, o, 64);
    if (lane == 0) wsum[wave] = s;
    __syncthreads();
    if (t == 0) {
        float tot = 0.f;
#pragma unroll
        for (int w = 0; w < LOSS_THREADS / 64; ++w) tot += wsum[w];
        atomicAdd(out, tot * (1.0f / ((float)B * (float)K * (float)K)));
    }
}

// ---------------------------------------------------------------------------
extern "C" void kernel_launch(void* const* d_in, const int* in_sizes, int n_in,
                              void* d_out, int out_size, void* d_ws, size_t ws_size,
                              hipStream_t stream)
{
    const float* cur_reid = (const float*)d_in[0];
    const float* pre_reid = (const float*)d_in[1];
    const int*   cur_inds = (const int*)d_in[2];
    const int*   pre_inds = (const int*)d_in[3];
    const int*   cur_circ = (const int*)d_in[4];
    const int*   pre_circ = (const int*)d_in[5];
    const int*   tmask    = (const int*)d_in[6];
    float*       out      = (float*)d_out;

    unsigned short* curf = (unsigned short*)d_ws;            // B*KP*C bf16 = 512 KB
    unsigned short* pref = curf + (size_t)B * KP * C;        // another 512 KB

    // 4096 (b,k) rows / 4 rows per block = 1024 blocks
    gather_kernel<<<B * KP / 4, 256, 0, stream>>>(
        cur_reid, pre_reid, cur_inds, pre_inds, cur_circ, pre_circ, tmask,
        curf, pref, out);

    // 8192 tiles (32x32x8) / 16 waves per block = 512 blocks
    loss_kernel<<<512, LOSS_THREADS, 0, stream>>>(curf, pref, tmask, out);
}

// Round 3
// 175.671 us; speedup vs baseline: 1.0060x; 1.0060x over previous
//
#include <hip/hip_runtime.h>

// Problem constants (from reference setup_inputs)
#define B 8
#define C 64
#define H 152
#define W 272
#define HW (H * W)          // 41344
#define K 500
#define KP 512              // K padded to tile multiple
#define ALPHA 0.25f
#define PROB_MIN 1e-4f

typedef __attribute__((ext_vector_type(8))) short short8;   // 8 bf16 (4 VGPRs)
typedef __attribute__((ext_vector_type(4))) float floatx4;  // 4 fp32 acc

// fp32 -> bf16 round-to-nearest-even
__device__ __forceinline__ unsigned short f32_to_bf16(float f) {
    union { float f; unsigned int u; } v; v.f = f;
    unsigned int r = v.u + 0x7FFFu + ((v.u >> 16) & 1u);
    return (unsigned short)(r >> 16);
}

// ---------------------------------------------------------------------------
// Kernel 1: masked gather -> bf16 feats [B, KP, C]; zero-pads rows K..KP-1.
// V4: each thread handles TWO (b,k) rows x both tensors -> 4 independent
// scattered loads in flight per thread. 2048 waves, 512 blocks.
// Index/mask loads are wave-uniform (row = t>>6) -> scalar path.
// Also zero-initializes the scalar output (poisoned before replay).
// ---------------------------------------------------------------------------
__global__ __launch_bounds__(256) void gather_kernel(
    const float* __restrict__ cur_reid,
    const float* __restrict__ pre_reid,
    const int* __restrict__ cur_inds,
    const int* __restrict__ pre_inds,
    const int* __restrict__ cur_circ,
    const int* __restrict__ pre_circ,
    const int* __restrict__ tmask,
    unsigned short* __restrict__ curf,
    unsigned short* __restrict__ pref,
    float* __restrict__ out)
{
    const int t = threadIdx.x;          // 0 .. 255
    const int r = t >> 6;               // 0..3 (wave-uniform)
    const int c = t & 63;               // channel = lane

    if (blockIdx.x == 0 && t == 0) out[0] = 0.0f;  // before loss kernel

    // Two rows per thread: bk0 and bk0+4 (both wave-uniform per wave)
    int  row[2];
    row[0] = blockIdx.x * 8 + r;
    row[1] = row[0] + 4;

    int   bvec[2], ci[2], pi[2];
    bool  pad[2];
#pragma unroll
    for (int i = 0; i < 2; ++i) {
        const int bk = row[i];
        const int b  = bk >> 9;         // /KP
        const int k  = bk & (KP - 1);
        bvec[i] = b;
        pad[i]  = (k >= K);
        if (!pad[i]) {
            const int bk_in = b * K + k;            // wave-uniform
            const int m  = tmask[bk_in];
            int c0 = m ? cur_inds[bk_in] : cur_circ[bk_in];
            int p0 = m ? pre_inds[bk_in] : pre_circ[bk_in];
            ci[i] = __builtin_amdgcn_readfirstlane(c0);   // provably uniform
            pi[i] = __builtin_amdgcn_readfirstlane(p0);
        }
    }

    // Issue all 4 scattered loads before any convert/store (max MLP)
    float cv[2], pv[2];
#pragma unroll
    for (int i = 0; i < 2; ++i) {
        if (!pad[i]) {
            const size_t plane = ((size_t)(bvec[i] * C + c)) * HW;
            cv[i] = cur_reid[plane + ci[i]];
            pv[i] = pre_reid[plane + pi[i]];
        }
    }

#pragma unroll
    for (int i = 0; i < 2; ++i) {
        const size_t orow = (size_t)row[i] * C + c;
        if (pad[i]) {
            curf[orow] = 0;
            pref[orow] = 0;
        } else {
            curf[orow] = f32_to_bf16(cv[i]);
            pref[orow] = f32_to_bf16(pv[i]);
        }
    }
}

// ---------------------------------------------------------------------------
// Kernel 2: per-wave 16x32 strip (2 tiles) of sim via MFMA 16x16x32 bf16.
// A-fragment loaded once and reused across both tiles -> 6 loads + 4 MFMAs
// per wave (was 2 x (4 loads + 2 MFMAs)). Fused focal loss + block reduce +
// one atomicAdd per block. Diagonal handling at tile granularity.
// ---------------------------------------------------------------------------
__device__ __forceinline__ float focal_term(float x, int gt, bool valid)
{
    if (!valid) return 0.0f;
    const float sim = 1.0f / (1.0f + __expf(-x));
    float p = gt ? sim : 1.0f - sim;
    p = fminf(fmaxf(p, PROB_MIN), 1.0f);
    const float a = gt ? ALPHA : (1.0f - ALPHA);
    const float om = 1.0f - p;
    return a * om * om * (-__logf(p));
}

// Per-tile focal accumulation. C/D layout: col = lane&15, row = quad*4 + reg
// [measured m89/m91]. Diagonal branch is wave-uniform.
__device__ __forceinline__ float tile_loss(const floatx4& acc, int b, int ti,
                                           int tj, int m16, int quad,
                                           const int* __restrict__ tmask)
{
    const int gj = tj * 16 + m16;
    float s = 0.f;
    if (ti == tj) {
#pragma unroll
        for (int r = 0; r < 4; ++r) {
            const int gi = ti * 16 + quad * 4 + r;
            const int gt = (gi == gj) ? tmask[b * K + gi] : 0;
            s += focal_term(acc[r], gt, (gi < K) && (gj < K));
        }
    } else {
#pragma unroll
        for (int r = 0; r < 4; ++r) {
            const int gi = ti * 16 + quad * 4 + r;
            s += focal_term(acc[r], 0, (gi < K) && (gj < K));
        }
    }
    return s;
}

#define LOSS_THREADS 1024   // 16 waves per block -> 16 strips per block

__global__ __launch_bounds__(LOSS_THREADS) void loss_kernel(
    const unsigned short* __restrict__ curf,
    const unsigned short* __restrict__ pref,
    const int* __restrict__ tmask,
    float* __restrict__ out)
{
    __shared__ float wsum[LOSS_THREADS / 64];

    const int t    = threadIdx.x;
    const int wave = t >> 6;
    const int lane = t & 63;

    // Strip id -> (b, ti, tj-pair). Per batch: 32 ti x 16 tj-pairs = 512.
    const int wid = blockIdx.x * (LOSS_THREADS / 64) + wave;  // 0..4095
    const int b   = wid >> 9;
    const int rem = wid & 511;
    const int ti  = rem >> 4;
    const int tj0 = (rem & 15) * 2;     // tiles tj0, tj0+1

    const int m16  = lane & 15;
    const int quad = lane >> 4;

    // A frag (reused for both tiles): curf[b][ti*16+m16][quad*8 ..]
    const unsigned short* pa = curf + (((size_t)(b * KP + ti * 16 + m16)) * C + quad * 8);
    const unsigned short* pb = pref + (((size_t)(b * KP + tj0 * 16 + m16)) * C + quad * 8);
    const short8 a0  = *(const short8*)pa;
    const short8 a1  = *(const short8*)(pa + 32);
    const short8 b00 = *(const short8*)pb;
    const short8 b01 = *(const short8*)(pb + 32);
    const short8 b10 = *(const short8*)(pb + (size_t)16 * C);        // tile tj0+1
    const short8 b11 = *(const short8*)(pb + (size_t)16 * C + 32);

    floatx4 acc0 = {0.f, 0.f, 0.f, 0.f};
    floatx4 acc1 = {0.f, 0.f, 0.f, 0.f};
    acc0 = __builtin_amdgcn_mfma_f32_16x16x32_bf16(a0, b00, acc0, 0, 0, 0);
    acc0 = __builtin_amdgcn_mfma_f32_16x16x32_bf16(a1, b01, acc0, 0, 0, 0);
    acc1 = __builtin_amdgcn_mfma_f32_16x16x32_bf16(a0, b10, acc1, 0, 0, 0);
    acc1 = __builtin_amdgcn_mfma_f32_16x16x32_bf16(a1, b11, acc1, 0, 0, 0);

    float s = tile_loss(acc0, b, ti, tj0,     m16, quad, tmask)
            + tile_loss(acc1, b, ti, tj0 + 1, m16, quad, tmask);

    // wave64 butterfly, then cross-wave via LDS, one atomic per block
#pragma unroll
    for (int o = 32; o > 0; o >>= 1) s += __shfl_down(s, o, 64);
    if (lane == 0) wsum[wave] = s;
    __syncthreads();
    if (t == 0) {
        float tot = 0.f;
#pragma unroll
        for (int w = 0; w < LOSS_THREADS / 64; ++w) tot += wsum[w];
        atomicAdd(out, tot * (1.0f / ((float)B * (float)K * (float)K)));
    }
}

// ---------------------------------------------------------------------------
extern "C" void kernel_launch(void* const* d_in, const int* in_sizes, int n_in,
                              void* d_out, int out_size, void* d_ws, size_t ws_size,
                              hipStream_t stream)
{
    const float* cur_reid = (const float*)d_in[0];
    const float* pre_reid = (const float*)d_in[1];
    const int*   cur_inds = (const int*)d_in[2];
    const int*   pre_inds = (const int*)d_in[3];
    const int*   cur_circ = (const int*)d_in[4];
    const int*   pre_circ = (const int*)d_in[5];
    const int*   tmask    = (const int*)d_in[6];
    float*       out      = (float*)d_out;

    unsigned short* curf = (unsigned short*)d_ws;            // B*KP*C bf16 = 512 KB
    unsigned short* pref = curf + (size_t)B * KP * C;        // another 512 KB

    // 4096 (b,k) rows / 8 rows per block = 512 blocks
    gather_kernel<<<B * KP / 8, 256, 0, stream>>>(
        cur_reid, pre_reid, cur_inds, pre_inds, cur_circ, pre_circ, tmask,
        curf, pref, out);

    // 4096 strips (2 tiles each) / 16 waves per block = 256 blocks
    loss_kernel<<<256, LOSS_THREADS, 0, stream>>>(curf, pref, tmask, out);
}